// Round 5
// baseline (509.446 us; speedup 1.0000x reference)
//
#include <hip/hip_runtime.h>

// ---------------------------------------------------------------------------
// HierarchicalCodebookGrounding — round 5: attn latency/locality fixes.
// B=16, N=4096, D=256, codes 672 (cat16|type128|var512|sp16).
//   qproj      : Qpack  = bf16(codes @ W^T + b)   in MFMA A-frag order
//   kproj_mfma : Kpack  = bf16(X @ k_w^T + k_b)   in MFMA B-frag order
//   xT_kern    : XTpack = bf16(X^T)               in MFMA B-frag order
//   attn_fused : grid (combo=b*4+nsl [64], m-tile [11]) — XCD-aligned K
//                sharing; kf ping-pong pipeline; xf prefetch; P via LDS;
//                O/lsum atomics into H. No S materialization.
//   hfinal_ip  : H /= lsum (in place); wraw = ||H||/tau
//   combine    : wave-parallel softmax/sparsify cascade + zero-skip z-sums
//   gate       : MLP + level combine + out proj + LN
// ---------------------------------------------------------------------------

#define DEV static __device__ __forceinline__

typedef short bf16x8 __attribute__((ext_vector_type(8)));
typedef float f32x4 __attribute__((ext_vector_type(4)));
typedef unsigned short u16x8 __attribute__((ext_vector_type(8)));

DEV float bf2f(unsigned short u) {
  return __uint_as_float(((unsigned int)u) << 16);
}
DEV unsigned short f2bf(float f) {
  unsigned int x = __float_as_uint(f);
  unsigned int r = (x + 0x7fffu + ((x >> 16) & 1u)) >> 16;
  return (unsigned short)r;
}

DEV bf16x8 pack8(const float4 a, const float4 b) {
  bf16x8 r;
  r[0] = (short)f2bf(a.x); r[1] = (short)f2bf(a.y);
  r[2] = (short)f2bf(a.z); r[3] = (short)f2bf(a.w);
  r[4] = (short)f2bf(b.x); r[5] = (short)f2bf(b.y);
  r[6] = (short)f2bf(b.z); r[7] = (short)f2bf(b.w);
  return r;
}

// packed fragment address (elements): row-tile rt, k-step ks
// layout: [rt][ks(8 per 256k)][64][8]; slot = (row&15) + 16*((k>>3)&3)
DEV size_t pk_off(int rt, int ks) { return ((size_t)rt * 8 + ks) * 512; }

// ---------------------------------------------------------------------------
// kproj_mfma: Kpack = bf16(X @ W^T + bias), rows m = b*4096+n (65536),
// cols c = 256. 128x128 tiles, BK=64, padded LDS (stride 72). grid (512, 2).
// ---------------------------------------------------------------------------
__global__ __launch_bounds__(256) void kproj_mfma(
    const float* __restrict__ X, const float* __restrict__ W,
    const float* __restrict__ bias, unsigned short* __restrict__ Kp) {
  __shared__ __align__(16) unsigned short As[128 * 72];
  __shared__ __align__(16) unsigned short Bs[128 * 72];
  const int m0 = blockIdx.x * 128, c0 = blockIdx.y * 128;
  const int t = threadIdx.x, l = t & 63, w = t >> 6;
  const int wm = (w & 1) * 64, wn = (w >> 1) * 64;
  const f32x4 zero = {0.f, 0.f, 0.f, 0.f};
  f32x4 acc[4][4];
#pragma unroll
  for (int i = 0; i < 4; ++i)
#pragma unroll
    for (int j = 0; j < 4; ++j) acc[i][j] = zero;
  const int rr = t >> 3, cc = (t & 7) * 8;
  for (int kc = 0; kc < 256; kc += 64) {
    __syncthreads();
#pragma unroll
    for (int p = 0; p < 4; ++p) {
      const int r = p * 32 + rr;
      const float* xs = &X[(size_t)(m0 + r) * 256 + kc + cc];
      const float4 a0 = *(const float4*)&xs[0];
      const float4 a1 = *(const float4*)&xs[4];
      *(bf16x8*)&As[r * 72 + cc] = pack8(a0, a1);
      const float* wsrc = &W[(size_t)(c0 + r) * 256 + kc + cc];
      const float4 b0 = *(const float4*)&wsrc[0];
      const float4 b1 = *(const float4*)&wsrc[4];
      *(bf16x8*)&Bs[r * 72 + cc] = pack8(b0, b1);
    }
    __syncthreads();
#pragma unroll
    for (int ks = 0; ks < 2; ++ks) {
      const int koff = ks * 32 + ((l >> 4) & 3) * 8;
      bf16x8 a[4], b[4];
#pragma unroll
      for (int f = 0; f < 4; ++f)
        a[f] = *(const bf16x8*)&As[(wm + f * 16 + (l & 15)) * 72 + koff];
#pragma unroll
      for (int f = 0; f < 4; ++f)
        b[f] = *(const bf16x8*)&Bs[(wn + f * 16 + (l & 15)) * 72 + koff];
#pragma unroll
      for (int i = 0; i < 4; ++i)
#pragma unroll
        for (int j = 0; j < 4; ++j)
          acc[i][j] =
              __builtin_amdgcn_mfma_f32_16x16x32_bf16(a[i], b[j], acc[i][j],
                                                      0, 0, 0);
    }
  }
  const int q = (l >> 4) & 3;
#pragma unroll
  for (int j = 0; j < 4; ++j) {
    const int c = c0 + wn + j * 16 + (l & 15);
    const float bv = bias[c];
#pragma unroll
    for (int i = 0; i < 4; ++i) {
      const int mrow = m0 + wm + i * 16 + q * 4;
#pragma unroll
      for (int r = 0; r < 4; ++r) {
        const int m = mrow + r;
        Kp[pk_off(m >> 4, c >> 5) + ((m & 15) + 16 * ((c >> 3) & 3)) * 8 +
           (c & 7)] = f2bf(acc[i][j][r] + bv);
      }
    }
  }
}

// ---------------------------------------------------------------------------
// xT_kern: XTpack[b][d>>4][n>>5][slot][8] = bf16(X[b][n][d] transposed).
// grid (64, 4, 16).
// ---------------------------------------------------------------------------
__global__ __launch_bounds__(256) void xT_kern(const float* __restrict__ X,
                                               unsigned short* __restrict__ XTp) {
  __shared__ float Ls[64][65];
  const int tn = blockIdx.x, td = blockIdx.y, b = blockIdx.z;
  const int t = threadIdx.x;
  const int nl = t >> 2, dp = (t & 3) * 16;
  const float* src =
      X + ((size_t)b * 4096 + tn * 64 + nl) * 256 + td * 64 + dp;
#pragma unroll
  for (int v = 0; v < 4; ++v) {
    const float4 x = *(const float4*)&src[v * 4];
    Ls[nl][dp + v * 4 + 0] = x.x;
    Ls[nl][dp + v * 4 + 1] = x.y;
    Ls[nl][dp + v * 4 + 2] = x.z;
    Ls[nl][dp + v * 4 + 3] = x.w;
  }
  __syncthreads();
  const int dl = t >> 2, np = (t & 3) * 16;
  u16x8 h0, h1;
#pragma unroll
  for (int j = 0; j < 8; ++j) h0[j] = f2bf(Ls[np + j][dl]);
#pragma unroll
  for (int j = 0; j < 8; ++j) h1[j] = f2bf(Ls[np + 8 + j][dl]);
  const int d = td * 64 + dl;
  const int n0g = tn * 64 + np;
  const int n1g = n0g + 8;
  unsigned short* dst = XTp + (size_t)b * 1048576;
  const size_t o0 = (((size_t)(d >> 4) * 128) + (n0g >> 5)) * 512 +
                    ((d & 15) + 16 * ((n0g >> 3) & 3)) * 8;
  const size_t o1 = (((size_t)(d >> 4) * 128) + (n1g >> 5)) * 512 +
                    ((d & 15) + 16 * ((n1g >> 3) & 3)) * 8;
  *(u16x8*)&dst[o0] = h0;
  *(u16x8*)&dst[o1] = h1;
}

// ---------------------------------------------------------------------------
// qproj: Qpack[44 tiles][8][64][8] = bf16(code @ W^T + b), zero-pad m>=672.
// grid 704, block 256.
// ---------------------------------------------------------------------------
__global__ __launch_bounds__(256) void qproj_kern(
    const float* __restrict__ cat_codes, const float* __restrict__ type_codes,
    const float* __restrict__ var_codes, const float* __restrict__ sp_codes,
    const float* __restrict__ cat_w, const float* __restrict__ cat_b,
    const float* __restrict__ type_w, const float* __restrict__ type_b,
    const float* __restrict__ var_w, const float* __restrict__ var_b,
    const float* __restrict__ sp_w, const float* __restrict__ sp_b,
    unsigned short* __restrict__ Qp) {
  const int m = blockIdx.x;
  const int t = threadIdx.x;
  const size_t off = pk_off(m >> 4, t >> 5) +
                     ((m & 15) + 16 * ((t >> 3) & 3)) * 8 + (t & 7);
  if (m >= 672) {
    Qp[off] = 0;
    return;
  }
  const float* code;
  const float* W;
  const float* bias;
  if (m < 16)       { code = cat_codes  + m * 256;         W = cat_w;  bias = cat_b; }
  else if (m < 144) { code = type_codes + (m - 16) * 256;  W = type_w; bias = type_b; }
  else if (m < 656) { code = var_codes  + (m - 144) * 256; W = var_w;  bias = var_b; }
  else              { code = sp_codes   + (m - 656) * 256; W = sp_w;   bias = sp_b; }
  __shared__ float xs[256];
  xs[t] = code[t];
  __syncthreads();
  float a = bias[t];
  const float* wr = W + (size_t)t * 256;
  for (int k = 0; k < 256; k += 4) {
    const float4 w = *(const float4*)&wr[k];
    a = fmaf(w.x, xs[k], a);
    a = fmaf(w.y, xs[k + 1], a);
    a = fmaf(w.z, xs[k + 2], a);
    a = fmaf(w.w, xs[k + 3], a);
  }
  Qp[off] = f2bf(a);
}

// ---------------------------------------------------------------------------
// attn_fused: grid (64 combos, 11 m-tiles). combo = b*4 + n-slice(1024).
// Blocks sharing a K-slice are 64 apart in linear id -> same XCD slot.
// Q frags persistent; kf ping-pong pipelined; xf prefetched per chunk;
// P via padded LDS; O/lsum atomicAdd. block 256 (4 waves), 2 blocks/CU.
// ---------------------------------------------------------------------------
__global__ __launch_bounds__(256, 2) void attn_fused(
    const unsigned short* __restrict__ Qp, const unsigned short* __restrict__ Kp,
    const unsigned short* __restrict__ XTp,
    const unsigned char* __restrict__ mask, float* __restrict__ H,
    float* __restrict__ lsum) {
  __shared__ __align__(16) unsigned short Plds[64 * 72];
  __shared__ unsigned char msk[1024];
  const int combo = blockIdx.x;
  const int m0 = blockIdx.y * 64;
  const int b = combo >> 2;
  const int nbase = (combo & 3) * 1024;
  const int t = threadIdx.x, l = t & 63, w = t >> 6;
  const int l15 = l & 15, q = l >> 4;
  ((uchar4*)msk)[t] = ((const uchar4*)(mask + (size_t)b * 4096 + nbase))[t];
  const int mt_g = (m0 >> 4) + w;
  bf16x8 qf[8];
#pragma unroll
  for (int ks = 0; ks < 8; ++ks)
    qf[ks] = *(const bf16x8*)&Qp[pk_off(mt_g, ks) + l * 8];
  const f32x4 zero = {0.f, 0.f, 0.f, 0.f};
  f32x4 accO[4][4];
#pragma unroll
  for (int i = 0; i < 4; ++i)
#pragma unroll
    for (int j = 0; j < 4; ++j) accO[i][j] = zero;
  f32x4 rs = zero;
  const unsigned short* XTb = XTp + (size_t)b * 1048576;
  __syncthreads();
  for (int c = 0; c < 16; ++c) {
    const int nt0 = (nbase >> 4) + c * 4;   // n-tile base (16-wide)
    const int nst0 = (nbase >> 5) + c * 2;  // n-step base (32-wide)
    // ---- prefetch PV B-fragments (independent of S phase) ----
    bf16x8 xf[2][4];
#pragma unroll
    for (int ks2 = 0; ks2 < 2; ++ks2)
#pragma unroll
      for (int dj = 0; dj < 4; ++dj)
        xf[ks2][dj] = *(const bf16x8*)&XTb[((size_t)(4 * w + dj) * 128 +
                                            nst0 + ks2) * 512 + l * 8];
    // ---- S phase: pipelined kf (ping-pong) ----
    f32x4 accS[4];
#pragma unroll
    for (int f = 0; f < 4; ++f) accS[f] = zero;
    bf16x8 kfA[4], kfB[4];
#pragma unroll
    for (int f = 0; f < 4; ++f)
      kfA[f] = *(const bf16x8*)&Kp[pk_off(b * 256 + nt0 + f, 0) + l * 8];
#pragma unroll
    for (int ks = 0; ks < 8; ++ks) {
      const bf16x8* cur = (ks & 1) ? kfB : kfA;
      bf16x8* nxt = (ks & 1) ? kfA : kfB;
      if (ks < 7) {
#pragma unroll
        for (int f = 0; f < 4; ++f)
          nxt[f] =
              *(const bf16x8*)&Kp[pk_off(b * 256 + nt0 + f, ks + 1) + l * 8];
      }
#pragma unroll
      for (int f = 0; f < 4; ++f)
        accS[f] = __builtin_amdgcn_mfma_f32_16x16x32_bf16(qf[ks], cur[f],
                                                          accS[f], 0, 0, 0);
    }
    __syncthreads();  // previous chunk's PV finished reading Plds
    // ---- epilogue: exp + P -> LDS (C-layout rows, stride 72) ----
#pragma unroll
    for (int f = 0; f < 4; ++f) {
      const bool mk = msk[c * 64 + f * 16 + l15] != 0;
#pragma unroll
      for (int r = 0; r < 4; ++r) {
        float s = accS[f][r] * 0.0625f;
        s = fminf(fmaxf(s, -50.f), 50.f);
        if (!mk) s = -50.f;
        const float e = __expf(s);
        Plds[(w * 16 + q * 4 + r) * 72 + f * 16 + l15] = f2bf(e);
        rs[r] += e;
      }
    }
    __syncthreads();
    // ---- PV phase ----
#pragma unroll
    for (int ks2 = 0; ks2 < 2; ++ks2) {
      bf16x8 pf[4];
#pragma unroll
      for (int mt = 0; mt < 4; ++mt)
        pf[mt] = *(const bf16x8*)&Plds[(mt * 16 + l15) * 72 + ks2 * 32 + q * 8];
#pragma unroll
      for (int mt = 0; mt < 4; ++mt)
#pragma unroll
        for (int dj = 0; dj < 4; ++dj)
          accO[mt][dj] = __builtin_amdgcn_mfma_f32_16x16x32_bf16(
              pf[mt], xf[ks2][dj], accO[mt][dj], 0, 0, 0);
    }
  }
  // ---- lsum: reduce rs over the 16 lanes sharing each row ----
#pragma unroll
  for (int r = 0; r < 4; ++r) {
    float v = rs[r];
    v += __shfl_xor(v, 1, 64);
    v += __shfl_xor(v, 2, 64);
    v += __shfl_xor(v, 4, 64);
    v += __shfl_xor(v, 8, 64);
    const int m = m0 + w * 16 + q * 4 + r;
    if (l15 == 0 && m < 672) atomicAdd(&lsum[b * 672 + m], v);
  }
  // ---- O: atomicAdd into H (n-slices accumulate) ----
#pragma unroll
  for (int mt = 0; mt < 4; ++mt) {
    const int mbase = m0 + mt * 16 + q * 4;
#pragma unroll
    for (int dj = 0; dj < 4; ++dj) {
      const int d = w * 64 + dj * 16 + l15;
#pragma unroll
      for (int r = 0; r < 4; ++r) {
        const int m = mbase + r;
        if (m < 672)
          atomicAdd(&H[((size_t)b * 672 + m) * 256 + d], accO[mt][dj][r]);
      }
    }
  }
}

// ---------------------------------------------------------------------------
// hfinal_ip: H /= lsum in place; wraw = ||H|| / tau. grid 16*672.
// ---------------------------------------------------------------------------
__global__ __launch_bounds__(256) void hfinal_ip(
    float* __restrict__ H, const float* __restrict__ lsum,
    const float* __restrict__ log_tau, float* __restrict__ wraw) {
  const int bm = blockIdx.x;
  const int t = threadIdx.x;
  __shared__ float red[256];
  const float inv = 1.0f / lsum[bm];
  const float v = H[(size_t)bm * 256 + t] * inv;
  H[(size_t)bm * 256 + t] = v;
  red[t] = v * v;
  __syncthreads();
  for (int s = 128; s > 0; s >>= 1) {
    if (t < s) red[t] += red[t + s];
    __syncthreads();
  }
  if (t == 0) {
    const float tau = fminf(fmaxf(expf(log_tau[0]) + 0.1f, 0.1f), 2.0f);
    wraw[bm] = sqrtf(red[0]) / tau;
  }
}

// ---------------------------------------------------------------------------
// pospool: pos_acc[b][d] += masked sum of positions; cnt[b] += #mask.
// grid (16, 32), block 256.
// ---------------------------------------------------------------------------
__global__ __launch_bounds__(256) void pospool_kern(
    const float* __restrict__ pos, const unsigned char* __restrict__ mask,
    float* __restrict__ pacc, float* __restrict__ cnt) {
  const int b = blockIdx.x, seg = blockIdx.y, t = threadIdx.x;
  const int dg = t & 63;
  const int nl = t >> 6;
  const int n0 = seg * 128;
  float4 acc = make_float4(0.f, 0.f, 0.f, 0.f);
  float c = 0.f;
  const float* pb = pos + (size_t)b * 4096 * 256;
  for (int j = 0; j < 32; ++j) {
    const int n = n0 + j * 4 + nl;
    const unsigned char mk = mask[(size_t)b * 4096 + n];
    if (mk) {
      const float4 v = *(const float4*)&pb[(size_t)n * 256 + dg * 4];
      acc.x += v.x; acc.y += v.y; acc.z += v.z; acc.w += v.w;
      if (dg == 0) c += 1.f;
    }
  }
  __shared__ float4 red4[256];
  __shared__ float redc[4];
  red4[t] = acc;
  if (dg == 0) redc[nl] = c;
  __syncthreads();
  if (t < 64) {
    float4 s = red4[t];
    const float4 s1 = red4[t + 64], s2 = red4[t + 128], s3 = red4[t + 192];
    s.x += s1.x + s2.x + s3.x;
    s.y += s1.y + s2.y + s3.y;
    s.z += s1.z + s2.z + s3.z;
    s.w += s1.w + s2.w + s3.w;
    float* pa = pacc + b * 256 + t * 4;
    atomicAdd(pa + 0, s.x);
    atomicAdd(pa + 1, s.y);
    atomicAdd(pa + 2, s.z);
    atomicAdd(pa + 3, s.w);
    if (t == 0) atomicAdd(&cnt[b], redc[0] + redc[1] + redc[2] + redc[3]);
  }
}

DEV float wave_max(float v) {
#pragma unroll
  for (int m = 1; m < 64; m <<= 1) v = fmaxf(v, __shfl_xor(v, m, 64));
  return v;
}
DEV float wave_sum(float v) {
#pragma unroll
  for (int m = 1; m < 64; m <<= 1) v += __shfl_xor(v, m, 64);
  return v;
}

// ---------------------------------------------------------------------------
// combine: wave-parallel softmax/sparsify cascade + zero-skip z-sums. grid 16.
// ---------------------------------------------------------------------------
__global__ __launch_bounds__(256) void combine_kern(
    const float* __restrict__ wraw, const float* __restrict__ H,
    float* __restrict__ zbuf) {
  const int b = blockIdx.x, t = threadIdx.x, l = t & 63;
  __shared__ float wr[672];
  __shared__ float wsp[672];
  for (int i = t; i < 672; i += 256) wr[i] = wraw[b * 672 + i];
  __syncthreads();
  {
    const float v = (l < 16) ? wr[l] : -1e30f;
    const float mx = wave_max(v);
    const float e = (l < 16) ? expf(wr[l] - mx) : 0.f;
    const float s = wave_sum(e);
    float w = e / s;
    w = (w > 0.1f) ? w : 0.f;
    const float s2 = wave_sum(w);
    if (l < 16) wsp[l] = w / (s2 + 1e-8f);
  }
  __syncthreads();
  {
    const float L0 = wr[16 + l] * wsp[l >> 3];
    const float L1 = wr[16 + 64 + l] * wsp[(64 + l) >> 3];
    const float mx = wave_max(fmaxf(L0, L1));
    const float e0 = expf(L0 - mx), e1 = expf(L1 - mx);
    const float s = wave_sum(e0 + e1);
    float w0 = e0 / s, w1 = e1 / s;
    w0 = (w0 > 0.05f) ? w0 : 0.f;
    w1 = (w1 > 0.05f) ? w1 : 0.f;
    const float s2 = wave_sum(w0 + w1);
    const float inv2 = 1.f / (s2 + 1e-8f);
    wsp[16 + l] = w0 * inv2;
    wsp[16 + 64 + l] = w1 * inv2;
  }
  __syncthreads();
  {
    float Lv[8];
    float lm = -1e30f;
#pragma unroll
    for (int j = 0; j < 8; ++j) {
      const int i = l * 8 + j;
      Lv[j] = wr[144 + i] * wsp[16 + (i >> 2)];
      lm = fmaxf(lm, Lv[j]);
    }
    const float mx = wave_max(lm);
    float ls = 0.f;
#pragma unroll
    for (int j = 0; j < 8; ++j) {
      Lv[j] = expf(Lv[j] - mx);
      ls += Lv[j];
    }
    const float s = wave_sum(ls);
    const float inv = 1.f / s;
    float ls2 = 0.f;
#pragma unroll
    for (int j = 0; j < 8; ++j) {
      float w = Lv[j] * inv;
      w = (w > 0.025f) ? w : 0.f;
      Lv[j] = w;
      ls2 += w;
    }
    const float s2 = wave_sum(ls2);
    const float inv2 = 1.f / (s2 + 1e-8f);
#pragma unroll
    for (int j = 0; j < 8; ++j) wsp[144 + l * 8 + j] = Lv[j] * inv2;
  }
  __syncthreads();
  {
    const float v = (l < 16) ? wr[656 + l] : -1e30f;
    const float mx = wave_max(v);
    const float e = (l < 16) ? expf(wr[656 + l] - mx) : 0.f;
    const float s = wave_sum(e);
    float w = e / s;
    w = (w > 0.1f) ? w : 0.f;
    const float s2 = wave_sum(w);
    if (l < 16) wsp[656 + l] = w / (s2 + 1e-8f);
  }
  __syncthreads();
  const float* Hb = H + (size_t)b * 672 * 256 + t;
  float z0 = 0.f, z1 = 0.f, z2 = 0.f, z3 = 0.f;
  for (int m = 0; m < 16; ++m) {
    const float wv = wsp[m];
    if (wv != 0.f) z0 = fmaf(wv, Hb[(size_t)m * 256], z0);
  }
  for (int m = 0; m < 128; ++m) {
    const float wv = wsp[16 + m];
    if (wv != 0.f) z1 = fmaf(wv, Hb[(size_t)(16 + m) * 256], z1);
  }
  for (int m = 0; m < 512; ++m) {
    const float wv = wsp[144 + m];
    if (wv != 0.f) z2 = fmaf(wv, Hb[(size_t)(144 + m) * 256], z2);
  }
  for (int m = 0; m < 16; ++m) {
    const float wv = wsp[656 + m];
    if (wv != 0.f) z3 = fmaf(wv, Hb[(size_t)(656 + m) * 256], z3);
  }
  zbuf[(b * 4 + 0) * 256 + t] = z0;
  zbuf[(b * 4 + 1) * 256 + t] = z1;
  zbuf[(b * 4 + 2) * 256 + t] = z2;
  zbuf[(b * 4 + 3) * 256 + t] = z3;
}

// ---------------------------------------------------------------------------
// gate: pos-gate MLP, level combine, out proj, layernorm. grid 16.
// ---------------------------------------------------------------------------
__global__ __launch_bounds__(256) void gate_kern(
    const float* __restrict__ zbuf, const float* __restrict__ pacc,
    const float* __restrict__ cnt, const float* __restrict__ g1_w,
    const float* __restrict__ g1_b, const float* __restrict__ g2_w,
    const float* __restrict__ g2_b, const float* __restrict__ out_w,
    const float* __restrict__ out_b, const float* __restrict__ ln_g,
    const float* __restrict__ ln_b, const float* __restrict__ lvlw,
    float* __restrict__ out) {
  const int b = blockIdx.x, t = threadIdx.x;
  __shared__ float gin[512];
  __shared__ float hb[256];
  __shared__ float zc[256];
  __shared__ float red[256];
  const float z0 = zbuf[(b * 4 + 0) * 256 + t];
  gin[t] = z0;
  const float c = fmaxf(cnt[b], 1.0f);
  gin[256 + t] = pacc[b * 256 + t] / c;
  __syncthreads();
  float a = g1_b[t];
  const float* w1 = g1_w + (size_t)t * 512;
  for (int k = 0; k < 512; k += 4) {
    const float4 w = *(const float4*)&w1[k];
    a = fmaf(w.x, gin[k], a);
    a = fmaf(w.y, gin[k + 1], a);
    a = fmaf(w.z, gin[k + 2], a);
    a = fmaf(w.w, gin[k + 3], a);
  }
  const float hg = 0.5f * a * (1.0f + erff(a * 0.7071067811865475f));
  hb[t] = hg;
  __syncthreads();
  float a2 = g2_b[t];
  const float* w2 = g2_w + (size_t)t * 256;
  for (int k = 0; k < 256; k += 4) {
    const float4 w = *(const float4*)&w2[k];
    a2 = fmaf(w.x, hb[k], a2);
    a2 = fmaf(w.y, hb[k + 1], a2);
    a2 = fmaf(w.z, hb[k + 2], a2);
    a2 = fmaf(w.w, hb[k + 3], a2);
  }
  const float pg = 1.0f / (1.0f + expf(-a2));
  const float l0 = lvlw[0], l1 = lvlw[1], l2 = lvlw[2], l3 = lvlw[3];
  const float mx = fmaxf(fmaxf(l0, l1), fmaxf(l2, l3));
  const float e0 = expf(l0 - mx), e1 = expf(l1 - mx);
  const float e2 = expf(l2 - mx), e3 = expf(l3 - mx);
  const float einv = 1.0f / (e0 + e1 + e2 + e3);
  const float zmix = (e0 * z0 * pg + e1 * zbuf[(b * 4 + 1) * 256 + t] +
                      e2 * zbuf[(b * 4 + 2) * 256 + t] +
                      e3 * zbuf[(b * 4 + 3) * 256 + t]) * einv;
  zc[t] = zmix;
  __syncthreads();
  float o = out_b[t];
  const float* wo = out_w + (size_t)t * 256;
  for (int k = 0; k < 256; k += 4) {
    const float4 w = *(const float4*)&wo[k];
    o = fmaf(w.x, zc[k], o);
    o = fmaf(w.y, zc[k + 1], o);
    o = fmaf(w.z, zc[k + 2], o);
    o = fmaf(w.w, zc[k + 3], o);
  }
  red[t] = o;
  __syncthreads();
  for (int s = 128; s > 0; s >>= 1) {
    if (t < s) red[t] += red[t + s];
    __syncthreads();
  }
  const float mu = red[0] / 256.f;
  __syncthreads();
  red[t] = o * o;
  __syncthreads();
  for (int s = 128; s > 0; s >>= 1) {
    if (t < s) red[t] += red[t + s];
    __syncthreads();
  }
  const float var = red[0] / 256.f - mu * mu;
  out[b * 256 + t] = (o - mu) * rsqrtf(var + 1e-5f) * ln_g[t] + ln_b[t];
}

// ---------------------------------------------------------------------------
// launch
// ---------------------------------------------------------------------------
extern "C" void kernel_launch(void* const* d_in, const int* in_sizes, int n_in,
                              void* d_out, int out_size, void* d_ws,
                              size_t ws_size, hipStream_t stream) {
  (void)in_sizes; (void)n_in; (void)out_size; (void)ws_size;
  const float* X          = (const float*)d_in[0];
  const float* positions  = (const float*)d_in[1];
  const float* cat_codes  = (const float*)d_in[2];
  const float* type_codes = (const float*)d_in[3];
  const float* var_codes  = (const float*)d_in[4];
  const float* sp_codes   = (const float*)d_in[5];
  const float* log_tau    = (const float*)d_in[6];
  const float* cat_w      = (const float*)d_in[7];
  const float* cat_b      = (const float*)d_in[8];
  const float* type_w     = (const float*)d_in[9];
  const float* type_b     = (const float*)d_in[10];
  const float* var_w      = (const float*)d_in[11];
  const float* var_b      = (const float*)d_in[12];
  const float* sp_w       = (const float*)d_in[13];
  const float* sp_b       = (const float*)d_in[14];
  const float* k_w        = (const float*)d_in[15];
  const float* k_b        = (const float*)d_in[16];
  const float* g1_w       = (const float*)d_in[17];
  const float* g1_b       = (const float*)d_in[18];
  const float* g2_w       = (const float*)d_in[19];
  const float* g2_b       = (const float*)d_in[20];
  const float* out_w      = (const float*)d_in[21];
  const float* out_b      = (const float*)d_in[22];
  const float* ln_g       = (const float*)d_in[23];
  const float* ln_b       = (const float*)d_in[24];
  const float* lvlw       = (const float*)d_in[25];
  const unsigned char* mask = (const unsigned char*)d_in[26];

  char* ws = (char*)d_ws;
  constexpr size_t O_KP  = 0;          // bf16 Kpack  [16*256][8][64][8] = 33,554,432
  constexpr size_t O_XT  = 33554432;   // bf16 XTpack [16][16][128][512] = 33,554,432
  constexpr size_t O_QP  = 67108864;   // bf16 Qpack  [44][8][64][8]     = 360,448
  constexpr size_t O_H   = 67469312;   // f32 H [16][672][256]           = 11,010,048
  constexpr size_t O_L   = 78479360;   // f32 lsum [16][672]
  constexpr size_t O_WR  = 78522368;   // f32 wraw [16][672]
  constexpr size_t O_PA  = 78565376;   // f32 pacc [16][256]
  constexpr size_t O_CNT = 78581760;   // f32 cnt [16]
  constexpr size_t O_Z   = 78581824;   // f32 zbuf [16][4][256]

  unsigned short* Kp  = (unsigned short*)(ws + O_KP);
  unsigned short* XTp = (unsigned short*)(ws + O_XT);
  unsigned short* Qp  = (unsigned short*)(ws + O_QP);
  float* H            = (float*)(ws + O_H);
  float* lsum         = (float*)(ws + O_L);
  float* wraw         = (float*)(ws + O_WR);
  float* pacc         = (float*)(ws + O_PA);
  float* cnt          = (float*)(ws + O_CNT);
  float* zbuf         = (float*)(ws + O_Z);
  float* out          = (float*)d_out;

  hipMemsetAsync(lsum, 0, 16 * 672 * 4, stream);
  hipMemsetAsync(H, 0, 11010048, stream);
  hipMemsetAsync(pacc, 0, 16 * 256 * 4, stream);
  hipMemsetAsync(cnt, 0, 64, stream);

  qproj_kern<<<dim3(704), 256, 0, stream>>>(
      cat_codes, type_codes, var_codes, sp_codes, cat_w, cat_b, type_w, type_b,
      var_w, var_b, sp_w, sp_b, Qp);
  kproj_mfma<<<dim3(512, 2), 256, 0, stream>>>(X, k_w, k_b, Kp);
  xT_kern<<<dim3(64, 4, 16), 256, 0, stream>>>(X, XTp);
  pospool_kern<<<dim3(16, 32), 256, 0, stream>>>(positions, mask, pacc, cnt);

  attn_fused<<<dim3(64, 11), 256, 0, stream>>>(Qp, Kp, XTp, mask, H, lsum);

  hfinal_ip<<<dim3(16 * 672), 256, 0, stream>>>(H, lsum, log_tau, wraw);
  combine_kern<<<dim3(16), 256, 0, stream>>>(wraw, H, zbuf);
  gate_kern<<<dim3(16), 256, 0, stream>>>(zbuf, pacc, cnt, g1_w, g1_b, g2_w,
                                          g2_b, out_w, out_b, ln_g, ln_b, lvlw,
                                          out);
}

// Round 6
// 446.796 us; speedup vs baseline: 1.1402x; 1.1402x over previous
//
#include <hip/hip_runtime.h>

// ---------------------------------------------------------------------------
// HierarchicalCodebookGrounding — round 6: attn K-operand via global_load_lds
// double-buffered DMA (m97 pattern). B=16, N=4096, D=256, codes 672.
//   qproj      : Qpack  = bf16(codes @ W^T + b)   in MFMA A-frag order
//   kproj_mfma : Kpack  = bf16(X @ k_w^T + k_b)   in MFMA B-frag order
//   xT_kern    : XTpack = bf16(X^T)               in MFMA B-frag order
//   attn_fused : grid (combo=b*4+nsl [64], m-tile [11]). Per 64-n chunk:
//                K staged 32KB -> LDS via DMA (dbuf, drained by next-chunk
//                barrier, hidden behind PV); S from LDS; P via padded LDS;
//                O/lsum atomics into H.
//   hfinal_ip  : H /= lsum (in place); wraw = ||H||/tau
//   combine    : wave-parallel softmax/sparsify cascade + zero-skip z-sums
//   gate       : MLP + level combine + out proj + LN
// ---------------------------------------------------------------------------

#define DEV static __device__ __forceinline__

typedef short bf16x8 __attribute__((ext_vector_type(8)));
typedef float f32x4 __attribute__((ext_vector_type(4)));
typedef unsigned short u16x8 __attribute__((ext_vector_type(8)));

DEV float bf2f(unsigned short u) {
  return __uint_as_float(((unsigned int)u) << 16);
}
DEV unsigned short f2bf(float f) {
  unsigned int x = __float_as_uint(f);
  unsigned int r = (x + 0x7fffu + ((x >> 16) & 1u)) >> 16;
  return (unsigned short)r;
}

// async global->LDS, 16B per lane; LDS dest = wave-uniform base + lane*16
DEV void gl2lds16(const void* g, void* l) {
  __builtin_amdgcn_global_load_lds(
      (const __attribute__((address_space(1))) unsigned int*)g,
      (__attribute__((address_space(3))) unsigned int*)l, 16, 0, 0);
}

DEV bf16x8 pack8(const float4 a, const float4 b) {
  bf16x8 r;
  r[0] = (short)f2bf(a.x); r[1] = (short)f2bf(a.y);
  r[2] = (short)f2bf(a.z); r[3] = (short)f2bf(a.w);
  r[4] = (short)f2bf(b.x); r[5] = (short)f2bf(b.y);
  r[6] = (short)f2bf(b.z); r[7] = (short)f2bf(b.w);
  return r;
}

// packed fragment address (elements): row-tile rt, k-step ks
// layout: [rt][ks(8 per 256k)][64][8]; slot = (row&15) + 16*((k>>3)&3)
DEV size_t pk_off(int rt, int ks) { return ((size_t)rt * 8 + ks) * 512; }

// ---------------------------------------------------------------------------
// kproj_mfma: Kpack = bf16(X @ W^T + bias), rows m = b*4096+n (65536),
// cols c = 256. 128x128 tiles, BK=64, padded LDS (stride 72). grid (512, 2).
// ---------------------------------------------------------------------------
__global__ __launch_bounds__(256) void kproj_mfma(
    const float* __restrict__ X, const float* __restrict__ W,
    const float* __restrict__ bias, unsigned short* __restrict__ Kp) {
  __shared__ __align__(16) unsigned short As[128 * 72];
  __shared__ __align__(16) unsigned short Bs[128 * 72];
  const int m0 = blockIdx.x * 128, c0 = blockIdx.y * 128;
  const int t = threadIdx.x, l = t & 63, w = t >> 6;
  const int wm = (w & 1) * 64, wn = (w >> 1) * 64;
  const f32x4 zero = {0.f, 0.f, 0.f, 0.f};
  f32x4 acc[4][4];
#pragma unroll
  for (int i = 0; i < 4; ++i)
#pragma unroll
    for (int j = 0; j < 4; ++j) acc[i][j] = zero;
  const int rr = t >> 3, cc = (t & 7) * 8;
  for (int kc = 0; kc < 256; kc += 64) {
    __syncthreads();
#pragma unroll
    for (int p = 0; p < 4; ++p) {
      const int r = p * 32 + rr;
      const float* xs = &X[(size_t)(m0 + r) * 256 + kc + cc];
      const float4 a0 = *(const float4*)&xs[0];
      const float4 a1 = *(const float4*)&xs[4];
      *(bf16x8*)&As[r * 72 + cc] = pack8(a0, a1);
      const float* wsrc = &W[(size_t)(c0 + r) * 256 + kc + cc];
      const float4 b0 = *(const float4*)&wsrc[0];
      const float4 b1 = *(const float4*)&wsrc[4];
      *(bf16x8*)&Bs[r * 72 + cc] = pack8(b0, b1);
    }
    __syncthreads();
#pragma unroll
    for (int ks = 0; ks < 2; ++ks) {
      const int koff = ks * 32 + ((l >> 4) & 3) * 8;
      bf16x8 a[4], b[4];
#pragma unroll
      for (int f = 0; f < 4; ++f)
        a[f] = *(const bf16x8*)&As[(wm + f * 16 + (l & 15)) * 72 + koff];
#pragma unroll
      for (int f = 0; f < 4; ++f)
        b[f] = *(const bf16x8*)&Bs[(wn + f * 16 + (l & 15)) * 72 + koff];
#pragma unroll
      for (int i = 0; i < 4; ++i)
#pragma unroll
        for (int j = 0; j < 4; ++j)
          acc[i][j] =
              __builtin_amdgcn_mfma_f32_16x16x32_bf16(a[i], b[j], acc[i][j],
                                                      0, 0, 0);
    }
  }
  const int q = (l >> 4) & 3;
#pragma unroll
  for (int j = 0; j < 4; ++j) {
    const int c = c0 + wn + j * 16 + (l & 15);
    const float bv = bias[c];
#pragma unroll
    for (int i = 0; i < 4; ++i) {
      const int mrow = m0 + wm + i * 16 + q * 4;
#pragma unroll
      for (int r = 0; r < 4; ++r) {
        const int m = mrow + r;
        Kp[pk_off(m >> 4, c >> 5) + ((m & 15) + 16 * ((c >> 3) & 3)) * 8 +
           (c & 7)] = f2bf(acc[i][j][r] + bv);
      }
    }
  }
}

// ---------------------------------------------------------------------------
// xT_kern: XTpack[b][d>>4][n>>5][slot][8] = bf16(X[b][n][d] transposed).
// grid (64, 4, 16).
// ---------------------------------------------------------------------------
__global__ __launch_bounds__(256) void xT_kern(const float* __restrict__ X,
                                               unsigned short* __restrict__ XTp) {
  __shared__ float Ls[64][65];
  const int tn = blockIdx.x, td = blockIdx.y, b = blockIdx.z;
  const int t = threadIdx.x;
  const int nl = t >> 2, dp = (t & 3) * 16;
  const float* src =
      X + ((size_t)b * 4096 + tn * 64 + nl) * 256 + td * 64 + dp;
#pragma unroll
  for (int v = 0; v < 4; ++v) {
    const float4 x = *(const float4*)&src[v * 4];
    Ls[nl][dp + v * 4 + 0] = x.x;
    Ls[nl][dp + v * 4 + 1] = x.y;
    Ls[nl][dp + v * 4 + 2] = x.z;
    Ls[nl][dp + v * 4 + 3] = x.w;
  }
  __syncthreads();
  const int dl = t >> 2, np = (t & 3) * 16;
  u16x8 h0, h1;
#pragma unroll
  for (int j = 0; j < 8; ++j) h0[j] = f2bf(Ls[np + j][dl]);
#pragma unroll
  for (int j = 0; j < 8; ++j) h1[j] = f2bf(Ls[np + 8 + j][dl]);
  const int d = td * 64 + dl;
  const int n0g = tn * 64 + np;
  const int n1g = n0g + 8;
  unsigned short* dst = XTp + (size_t)b * 1048576;
  const size_t o0 = (((size_t)(d >> 4) * 128) + (n0g >> 5)) * 512 +
                    ((d & 15) + 16 * ((n0g >> 3) & 3)) * 8;
  const size_t o1 = (((size_t)(d >> 4) * 128) + (n1g >> 5)) * 512 +
                    ((d & 15) + 16 * ((n1g >> 3) & 3)) * 8;
  *(u16x8*)&dst[o0] = h0;
  *(u16x8*)&dst[o1] = h1;
}

// ---------------------------------------------------------------------------
// qproj: Qpack[44 tiles][8][64][8] = bf16(code @ W^T + b), zero-pad m>=672.
// grid 704, block 256.
// ---------------------------------------------------------------------------
__global__ __launch_bounds__(256) void qproj_kern(
    const float* __restrict__ cat_codes, const float* __restrict__ type_codes,
    const float* __restrict__ var_codes, const float* __restrict__ sp_codes,
    const float* __restrict__ cat_w, const float* __restrict__ cat_b,
    const float* __restrict__ type_w, const float* __restrict__ type_b,
    const float* __restrict__ var_w, const float* __restrict__ var_b,
    const float* __restrict__ sp_w, const float* __restrict__ sp_b,
    unsigned short* __restrict__ Qp) {
  const int m = blockIdx.x;
  const int t = threadIdx.x;
  const size_t off = pk_off(m >> 4, t >> 5) +
                     ((m & 15) + 16 * ((t >> 3) & 3)) * 8 + (t & 7);
  if (m >= 672) {
    Qp[off] = 0;
    return;
  }
  const float* code;
  const float* W;
  const float* bias;
  if (m < 16)       { code = cat_codes  + m * 256;         W = cat_w;  bias = cat_b; }
  else if (m < 144) { code = type_codes + (m - 16) * 256;  W = type_w; bias = type_b; }
  else if (m < 656) { code = var_codes  + (m - 144) * 256; W = var_w;  bias = var_b; }
  else              { code = sp_codes   + (m - 656) * 256; W = sp_w;   bias = sp_b; }
  __shared__ float xs[256];
  xs[t] = code[t];
  __syncthreads();
  float a = bias[t];
  const float* wr = W + (size_t)t * 256;
  for (int k = 0; k < 256; k += 4) {
    const float4 w = *(const float4*)&wr[k];
    a = fmaf(w.x, xs[k], a);
    a = fmaf(w.y, xs[k + 1], a);
    a = fmaf(w.z, xs[k + 2], a);
    a = fmaf(w.w, xs[k + 3], a);
  }
  Qp[off] = f2bf(a);
}

// ---------------------------------------------------------------------------
// attn_fused: grid (64 combos, 11 m-tiles). combo = b*4 + n-slice(1024).
// Per 64-n chunk: K chunk (32KB, contiguous in Kp) DMA'd to LDS (dbuf);
// 2 barriers/chunk: C (top, drains DMA c + fences PV c-1), B (P visible).
// DMA for c+1 issues after B, drains at next C — hidden behind PV MFMAs.
// block 256 (4 waves), 2 blocks/CU.
// ---------------------------------------------------------------------------
__global__ __launch_bounds__(256, 2) void attn_fused(
    const unsigned short* __restrict__ Qp, const unsigned short* __restrict__ Kp,
    const unsigned short* __restrict__ XTp,
    const unsigned char* __restrict__ mask, float* __restrict__ H,
    float* __restrict__ lsum) {
  __shared__ __align__(16) unsigned short Ks[2][16384];  // 2 x 32KB
  __shared__ __align__(16) unsigned short Plds[64 * 72];
  __shared__ unsigned char msk[1024];
  const int combo = blockIdx.x;
  const int m0 = blockIdx.y * 64;
  const int b = combo >> 2;
  const int nbase = (combo & 3) * 1024;
  const int t = threadIdx.x, l = t & 63, w = t >> 6;
  const int l15 = l & 15, q = l >> 4;
  ((uchar4*)msk)[t] = ((const uchar4*)(mask + (size_t)b * 4096 + nbase))[t];
  const int mt_g = (m0 >> 4) + w;
  bf16x8 qf[8];
#pragma unroll
  for (int ks = 0; ks < 8; ++ks)
    qf[ks] = *(const bf16x8*)&Qp[pk_off(mt_g, ks) + l * 8];
  const f32x4 zero = {0.f, 0.f, 0.f, 0.f};
  f32x4 accO[4][4];
#pragma unroll
  for (int i = 0; i < 4; ++i)
#pragma unroll
    for (int j = 0; j < 4; ++j) accO[i][j] = zero;
  f32x4 rs = zero;
  const unsigned short* XTb = XTp + (size_t)b * 1048576;
  // K chunk c is 32KB contiguous at Kp + (b*256 + nbase/16 + 4c)*4096 elems.
  const unsigned short* Kchunk0 = Kp + ((size_t)b * 256 + (nbase >> 4)) * 4096;
  // prologue: DMA chunk 0 into Ks[0]; wave w stages its 8KB quarter
#pragma unroll
  for (int i = 0; i < 8; ++i)
    gl2lds16(Kchunk0 + (w * 8 + i) * 512 + l * 8, &Ks[0][(w * 8 + i) * 512]);
  for (int c = 0; c < 16; ++c) {
    const int cur = c & 1;
    __syncthreads();  // C: drains DMA(c) (vmcnt0) + all waves past PV(c-1)
    // ---- prefetch PV B-fragments (independent; consumed after barrier B) --
    const int nst0 = (nbase >> 5) + c * 2;
    bf16x8 xf[2][4];
#pragma unroll
    for (int ks2 = 0; ks2 < 2; ++ks2)
#pragma unroll
      for (int dj = 0; dj < 4; ++dj)
        xf[ks2][dj] = *(const bf16x8*)&XTb[((size_t)(4 * w + dj) * 128 +
                                            nst0 + ks2) * 512 + l * 8];
    // ---- S phase from LDS ----
    f32x4 accS[4];
#pragma unroll
    for (int f = 0; f < 4; ++f) accS[f] = zero;
#pragma unroll
    for (int ks = 0; ks < 8; ++ks) {
      bf16x8 kf[4];
#pragma unroll
      for (int f = 0; f < 4; ++f)
        kf[f] = *(const bf16x8*)&Ks[cur][(f * 8 + ks) * 512 + l * 8];
#pragma unroll
      for (int f = 0; f < 4; ++f)
        accS[f] = __builtin_amdgcn_mfma_f32_16x16x32_bf16(qf[ks], kf[f],
                                                          accS[f], 0, 0, 0);
    }
    // ---- epilogue: exp + P -> LDS (C-layout rows, stride 72) ----
#pragma unroll
    for (int f = 0; f < 4; ++f) {
      const bool mk = msk[c * 64 + f * 16 + l15] != 0;
#pragma unroll
      for (int r = 0; r < 4; ++r) {
        float s = accS[f][r] * 0.0625f;
        s = fminf(fmaxf(s, -50.f), 50.f);
        if (!mk) s = -50.f;
        const float e = __expf(s);
        Plds[(w * 16 + q * 4 + r) * 72 + f * 16 + l15] = f2bf(e);
        rs[r] += e;
      }
    }
    __syncthreads();  // B: Plds visible (also drains xf loads - needed next)
    // ---- issue DMA for chunk c+1 (drains at next C, hidden behind PV) ----
    if (c < 15) {
      const unsigned short* src = Kchunk0 + (size_t)(c + 1) * 16384;
      unsigned short* dst = &Ks[1 - cur][0];
#pragma unroll
      for (int i = 0; i < 8; ++i)
        gl2lds16(src + (w * 8 + i) * 512 + l * 8, dst + (w * 8 + i) * 512);
    }
    // ---- PV phase ----
#pragma unroll
    for (int ks2 = 0; ks2 < 2; ++ks2) {
      bf16x8 pf[4];
#pragma unroll
      for (int mt = 0; mt < 4; ++mt)
        pf[mt] = *(const bf16x8*)&Plds[(mt * 16 + l15) * 72 + ks2 * 32 + q * 8];
#pragma unroll
      for (int mt = 0; mt < 4; ++mt)
#pragma unroll
        for (int dj = 0; dj < 4; ++dj)
          accO[mt][dj] = __builtin_amdgcn_mfma_f32_16x16x32_bf16(
              pf[mt], xf[ks2][dj], accO[mt][dj], 0, 0, 0);
    }
  }
  // ---- lsum: reduce rs over the 16 lanes sharing each row ----
#pragma unroll
  for (int r = 0; r < 4; ++r) {
    float v = rs[r];
    v += __shfl_xor(v, 1, 64);
    v += __shfl_xor(v, 2, 64);
    v += __shfl_xor(v, 4, 64);
    v += __shfl_xor(v, 8, 64);
    const int m = m0 + w * 16 + q * 4 + r;
    if (l15 == 0 && m < 672) atomicAdd(&lsum[b * 672 + m], v);
  }
  // ---- O: atomicAdd into H (n-slices accumulate) ----
#pragma unroll
  for (int mt = 0; mt < 4; ++mt) {
    const int mbase = m0 + mt * 16 + q * 4;
#pragma unroll
    for (int dj = 0; dj < 4; ++dj) {
      const int d = w * 64 + dj * 16 + l15;
#pragma unroll
      for (int r = 0; r < 4; ++r) {
        const int m = mbase + r;
        if (m < 672)
          atomicAdd(&H[((size_t)b * 672 + m) * 256 + d], accO[mt][dj][r]);
      }
    }
  }
}

// ---------------------------------------------------------------------------
// hfinal_ip: H /= lsum in place; wraw = ||H|| / tau. grid 16*672.
// ---------------------------------------------------------------------------
__global__ __launch_bounds__(256) void hfinal_ip(
    float* __restrict__ H, const float* __restrict__ lsum,
    const float* __restrict__ log_tau, float* __restrict__ wraw) {
  const int bm = blockIdx.x;
  const int t = threadIdx.x;
  __shared__ float red[256];
  const float inv = 1.0f / lsum[bm];
  const float v = H[(size_t)bm * 256 + t] * inv;
  H[(size_t)bm * 256 + t] = v;
  red[t] = v * v;
  __syncthreads();
  for (int s = 128; s > 0; s >>= 1) {
    if (t < s) red[t] += red[t + s];
    __syncthreads();
  }
  if (t == 0) {
    const float tau = fminf(fmaxf(expf(log_tau[0]) + 0.1f, 0.1f), 2.0f);
    wraw[bm] = sqrtf(red[0]) / tau;
  }
}

// ---------------------------------------------------------------------------
// pospool: pos_acc[b][d] += masked sum of positions; cnt[b] += #mask.
// grid (16, 32), block 256.
// ---------------------------------------------------------------------------
__global__ __launch_bounds__(256) void pospool_kern(
    const float* __restrict__ pos, const unsigned char* __restrict__ mask,
    float* __restrict__ pacc, float* __restrict__ cnt) {
  const int b = blockIdx.x, seg = blockIdx.y, t = threadIdx.x;
  const int dg = t & 63;
  const int nl = t >> 6;
  const int n0 = seg * 128;
  float4 acc = make_float4(0.f, 0.f, 0.f, 0.f);
  float c = 0.f;
  const float* pb = pos + (size_t)b * 4096 * 256;
  for (int j = 0; j < 32; ++j) {
    const int n = n0 + j * 4 + nl;
    const unsigned char mk = mask[(size_t)b * 4096 + n];
    if (mk) {
      const float4 v = *(const float4*)&pb[(size_t)n * 256 + dg * 4];
      acc.x += v.x; acc.y += v.y; acc.z += v.z; acc.w += v.w;
      if (dg == 0) c += 1.f;
    }
  }
  __shared__ float4 red4[256];
  __shared__ float redc[4];
  red4[t] = acc;
  if (dg == 0) redc[nl] = c;
  __syncthreads();
  if (t < 64) {
    float4 s = red4[t];
    const float4 s1 = red4[t + 64], s2 = red4[t + 128], s3 = red4[t + 192];
    s.x += s1.x + s2.x + s3.x;
    s.y += s1.y + s2.y + s3.y;
    s.z += s1.z + s2.z + s3.z;
    s.w += s1.w + s2.w + s3.w;
    float* pa = pacc + b * 256 + t * 4;
    atomicAdd(pa + 0, s.x);
    atomicAdd(pa + 1, s.y);
    atomicAdd(pa + 2, s.z);
    atomicAdd(pa + 3, s.w);
    if (t == 0) atomicAdd(&cnt[b], redc[0] + redc[1] + redc[2] + redc[3]);
  }
}

DEV float wave_max(float v) {
#pragma unroll
  for (int m = 1; m < 64; m <<= 1) v = fmaxf(v, __shfl_xor(v, m, 64));
  return v;
}
DEV float wave_sum(float v) {
#pragma unroll
  for (int m = 1; m < 64; m <<= 1) v += __shfl_xor(v, m, 64);
  return v;
}

// ---------------------------------------------------------------------------
// combine: wave-parallel softmax/sparsify cascade + zero-skip z-sums. grid 16.
// ---------------------------------------------------------------------------
__global__ __launch_bounds__(256) void combine_kern(
    const float* __restrict__ wraw, const float* __restrict__ H,
    float* __restrict__ zbuf) {
  const int b = blockIdx.x, t = threadIdx.x, l = t & 63;
  __shared__ float wr[672];
  __shared__ float wsp[672];
  for (int i = t; i < 672; i += 256) wr[i] = wraw[b * 672 + i];
  __syncthreads();
  {
    const float v = (l < 16) ? wr[l] : -1e30f;
    const float mx = wave_max(v);
    const float e = (l < 16) ? expf(wr[l] - mx) : 0.f;
    const float s = wave_sum(e);
    float w = e / s;
    w = (w > 0.1f) ? w : 0.f;
    const float s2 = wave_sum(w);
    if (l < 16) wsp[l] = w / (s2 + 1e-8f);
  }
  __syncthreads();
  {
    const float L0 = wr[16 + l] * wsp[l >> 3];
    const float L1 = wr[16 + 64 + l] * wsp[(64 + l) >> 3];
    const float mx = wave_max(fmaxf(L0, L1));
    const float e0 = expf(L0 - mx), e1 = expf(L1 - mx);
    const float s = wave_sum(e0 + e1);
    float w0 = e0 / s, w1 = e1 / s;
    w0 = (w0 > 0.05f) ? w0 : 0.f;
    w1 = (w1 > 0.05f) ? w1 : 0.f;
    const float s2 = wave_sum(w0 + w1);
    const float inv2 = 1.f / (s2 + 1e-8f);
    wsp[16 + l] = w0 * inv2;
    wsp[16 + 64 + l] = w1 * inv2;
  }
  __syncthreads();
  {
    float Lv[8];
    float lm = -1e30f;
#pragma unroll
    for (int j = 0; j < 8; ++j) {
      const int i = l * 8 + j;
      Lv[j] = wr[144 + i] * wsp[16 + (i >> 2)];
      lm = fmaxf(lm, Lv[j]);
    }
    const float mx = wave_max(lm);
    float ls = 0.f;
#pragma unroll
    for (int j = 0; j < 8; ++j) {
      Lv[j] = expf(Lv[j] - mx);
      ls += Lv[j];
    }
    const float s = wave_sum(ls);
    const float inv = 1.f / s;
    float ls2 = 0.f;
#pragma unroll
    for (int j = 0; j < 8; ++j) {
      float w = Lv[j] * inv;
      w = (w > 0.025f) ? w : 0.f;
      Lv[j] = w;
      ls2 += w;
    }
    const float s2 = wave_sum(ls2);
    const float inv2 = 1.f / (s2 + 1e-8f);
#pragma unroll
    for (int j = 0; j < 8; ++j) wsp[144 + l * 8 + j] = Lv[j] * inv2;
  }
  __syncthreads();
  {
    const float v = (l < 16) ? wr[656 + l] : -1e30f;
    const float mx = wave_max(v);
    const float e = (l < 16) ? expf(wr[656 + l] - mx) : 0.f;
    const float s = wave_sum(e);
    float w = e / s;
    w = (w > 0.1f) ? w : 0.f;
    const float s2 = wave_sum(w);
    if (l < 16) wsp[656 + l] = w / (s2 + 1e-8f);
  }
  __syncthreads();
  const float* Hb = H + (size_t)b * 672 * 256 + t;
  float z0 = 0.f, z1 = 0.f, z2 = 0.f, z3 = 0.f;
  for (int m = 0; m < 16; ++m) {
    const float wv = wsp[m];
    if (wv != 0.f) z0 = fmaf(wv, Hb[(size_t)m * 256], z0);
  }
  for (int m = 0; m < 128; ++m) {
    const float wv = wsp[16 + m];
    if (wv != 0.f) z1 = fmaf(wv, Hb[(size_t)(16 + m) * 256], z1);
  }
  for (int m = 0; m < 512; ++m) {
    const float wv = wsp[144 + m];
    if (wv != 0.f) z2 = fmaf(wv, Hb[(size_t)(144 + m) * 256], z2);
  }
  for (int m = 0; m < 16; ++m) {
    const float wv = wsp[656 + m];
    if (wv != 0.f) z3 = fmaf(wv, Hb[(size_t)(656 + m) * 256], z3);
  }
  zbuf[(b * 4 + 0) * 256 + t] = z0;
  zbuf[(b * 4 + 1) * 256 + t] = z1;
  zbuf[(b * 4 + 2) * 256 + t] = z2;
  zbuf[(b * 4 + 3) * 256 + t] = z3;
}

// ---------------------------------------------------------------------------
// gate: pos-gate MLP, level combine, out proj, layernorm. grid 16.
// ---------------------------------------------------------------------------
__global__ __launch_bounds__(256) void gate_kern(
    const float* __restrict__ zbuf, const float* __restrict__ pacc,
    const float* __restrict__ cnt, const float* __restrict__ g1_w,
    const float* __restrict__ g1_b, const float* __restrict__ g2_w,
    const float* __restrict__ g2_b, const float* __restrict__ out_w,
    const float* __restrict__ out_b, const float* __restrict__ ln_g,
    const float* __restrict__ ln_b, const float* __restrict__ lvlw,
    float* __restrict__ out) {
  const int b = blockIdx.x, t = threadIdx.x;
  __shared__ float gin[512];
  __shared__ float hb[256];
  __shared__ float zc[256];
  __shared__ float red[256];
  const float z0 = zbuf[(b * 4 + 0) * 256 + t];
  gin[t] = z0;
  const float c = fmaxf(cnt[b], 1.0f);
  gin[256 + t] = pacc[b * 256 + t] / c;
  __syncthreads();
  float a = g1_b[t];
  const float* w1 = g1_w + (size_t)t * 512;
  for (int k = 0; k < 512; k += 4) {
    const float4 w = *(const float4*)&w1[k];
    a = fmaf(w.x, gin[k], a);
    a = fmaf(w.y, gin[k + 1], a);
    a = fmaf(w.z, gin[k + 2], a);
    a = fmaf(w.w, gin[k + 3], a);
  }
  const float hg = 0.5f * a * (1.0f + erff(a * 0.7071067811865475f));
  hb[t] = hg;
  __syncthreads();
  float a2 = g2_b[t];
  const float* w2 = g2_w + (size_t)t * 256;
  for (int k = 0; k < 256; k += 4) {
    const float4 w = *(const float4*)&w2[k];
    a2 = fmaf(w.x, hb[k], a2);
    a2 = fmaf(w.y, hb[k + 1], a2);
    a2 = fmaf(w.z, hb[k + 2], a2);
    a2 = fmaf(w.w, hb[k + 3], a2);
  }
  const float pg = 1.0f / (1.0f + expf(-a2));
  const float l0 = lvlw[0], l1 = lvlw[1], l2 = lvlw[2], l3 = lvlw[3];
  const float mx = fmaxf(fmaxf(l0, l1), fmaxf(l2, l3));
  const float e0 = expf(l0 - mx), e1 = expf(l1 - mx);
  const float e2 = expf(l2 - mx), e3 = expf(l3 - mx);
  const float einv = 1.0f / (e0 + e1 + e2 + e3);
  const float zmix = (e0 * z0 * pg + e1 * zbuf[(b * 4 + 1) * 256 + t] +
                      e2 * zbuf[(b * 4 + 2) * 256 + t] +
                      e3 * zbuf[(b * 4 + 3) * 256 + t]) * einv;
  zc[t] = zmix;
  __syncthreads();
  float o = out_b[t];
  const float* wo = out_w + (size_t)t * 256;
  for (int k = 0; k < 256; k += 4) {
    const float4 w = *(const float4*)&wo[k];
    o = fmaf(w.x, zc[k], o);
    o = fmaf(w.y, zc[k + 1], o);
    o = fmaf(w.z, zc[k + 2], o);
    o = fmaf(w.w, zc[k + 3], o);
  }
  red[t] = o;
  __syncthreads();
  for (int s = 128; s > 0; s >>= 1) {
    if (t < s) red[t] += red[t + s];
    __syncthreads();
  }
  const float mu = red[0] / 256.f;
  __syncthreads();
  red[t] = o * o;
  __syncthreads();
  for (int s = 128; s > 0; s >>= 1) {
    if (t < s) red[t] += red[t + s];
    __syncthreads();
  }
  const float var = red[0] / 256.f - mu * mu;
  out[b * 256 + t] = (o - mu) * rsqrtf(var + 1e-5f) * ln_g[t] + ln_b[t];
}

// ---------------------------------------------------------------------------
// launch
// ---------------------------------------------------------------------------
extern "C" void kernel_launch(void* const* d_in, const int* in_sizes, int n_in,
                              void* d_out, int out_size, void* d_ws,
                              size_t ws_size, hipStream_t stream) {
  (void)in_sizes; (void)n_in; (void)out_size; (void)ws_size;
  const float* X          = (const float*)d_in[0];
  const float* positions  = (const float*)d_in[1];
  const float* cat_codes  = (const float*)d_in[2];
  const float* type_codes = (const float*)d_in[3];
  const float* var_codes  = (const float*)d_in[4];
  const float* sp_codes   = (const float*)d_in[5];
  const float* log_tau    = (const float*)d_in[6];
  const float* cat_w      = (const float*)d_in[7];
  const float* cat_b      = (const float*)d_in[8];
  const float* type_w     = (const float*)d_in[9];
  const float* type_b     = (const float*)d_in[10];
  const float* var_w      = (const float*)d_in[11];
  const float* var_b      = (const float*)d_in[12];
  const float* sp_w       = (const float*)d_in[13];
  const float* sp_b       = (const float*)d_in[14];
  const float* k_w        = (const float*)d_in[15];
  const float* k_b        = (const float*)d_in[16];
  const float* g1_w       = (const float*)d_in[17];
  const float* g1_b       = (const float*)d_in[18];
  const float* g2_w       = (const float*)d_in[19];
  const float* g2_b       = (const float*)d_in[20];
  const float* out_w      = (const float*)d_in[21];
  const float* out_b      = (const float*)d_in[22];
  const float* ln_g       = (const float*)d_in[23];
  const float* ln_b       = (const float*)d_in[24];
  const float* lvlw       = (const float*)d_in[25];
  const unsigned char* mask = (const unsigned char*)d_in[26];

  char* ws = (char*)d_ws;
  constexpr size_t O_KP  = 0;          // bf16 Kpack  [16*256][8][64][8] = 33,554,432
  constexpr size_t O_XT  = 33554432;   // bf16 XTpack [16][16][128][512] = 33,554,432
  constexpr size_t O_QP  = 67108864;   // bf16 Qpack  [44][8][64][8]     = 360,448
  constexpr size_t O_H   = 67469312;   // f32 H [16][672][256]           = 11,010,048
  constexpr size_t O_L   = 78479360;   // f32 lsum [16][672]
  constexpr size_t O_WR  = 78522368;   // f32 wraw [16][672]
  constexpr size_t O_PA  = 78565376;   // f32 pacc [16][256]
  constexpr size_t O_CNT = 78581760;   // f32 cnt [16]
  constexpr size_t O_Z   = 78581824;   // f32 zbuf [16][4][256]

  unsigned short* Kp  = (unsigned short*)(ws + O_KP);
  unsigned short* XTp = (unsigned short*)(ws + O_XT);
  unsigned short* Qp  = (unsigned short*)(ws + O_QP);
  float* H            = (float*)(ws + O_H);
  float* lsum         = (float*)(ws + O_L);
  float* wraw         = (float*)(ws + O_WR);
  float* pacc         = (float*)(ws + O_PA);
  float* cnt          = (float*)(ws + O_CNT);
  float* zbuf         = (float*)(ws + O_Z);
  float* out          = (float*)d_out;

  hipMemsetAsync(lsum, 0, 16 * 672 * 4, stream);
  hipMemsetAsync(H, 0, 11010048, stream);
  hipMemsetAsync(pacc, 0, 16 * 256 * 4, stream);
  hipMemsetAsync(cnt, 0, 64, stream);

  qproj_kern<<<dim3(704), 256, 0, stream>>>(
      cat_codes, type_codes, var_codes, sp_codes, cat_w, cat_b, type_w, type_b,
      var_w, var_b, sp_w, sp_b, Qp);
  kproj_mfma<<<dim3(512, 2), 256, 0, stream>>>(X, k_w, k_b, Kp);
  xT_kern<<<dim3(64, 4, 16), 256, 0, stream>>>(X, XTp);
  pospool_kern<<<dim3(16, 32), 256, 0, stream>>>(positions, mask, pacc, cnt);

  attn_fused<<<dim3(64, 11), 256, 0, stream>>>(Qp, Kp, XTp, mask, H, lsum);

  hfinal_ip<<<dim3(16 * 672), 256, 0, stream>>>(H, lsum, log_tau, wraw);
  combine_kern<<<dim3(16), 256, 0, stream>>>(wraw, H, zbuf);
  gate_kern<<<dim3(16), 256, 0, stream>>>(zbuf, pacc, cnt, g1_w, g1_b, g2_w,
                                          g2_b, out_w, out_b, ln_g, ln_b, lvlw,
                                          out);
}